// Round 1
// baseline (15.406 us; speedup 1.0000x reference)
//
#include <hip/hip_runtime.h>

#define NQ      8
#define NIN     128
#define NF      136          // NIN + NQ
#define BATCH   4096
#define ROWS    64           // rows per block
#define THREADS 256
#define CSTRIDE 140          // padded row stride for combined tile (16B aligned, conflict-free)

__device__ __forceinline__ float sigmoidf_(float v) {
    return 1.0f / (1.0f + __expf(-v));
}

__global__ __launch_bounds__(THREADS)
void qlstm_kernel(const float* __restrict__ x,
                  const float* __restrict__ h_prev,
                  const float* __restrict__ c_prev,
                  const float* __restrict__ Wf, const float* __restrict__ bf,
                  const float* __restrict__ Wi, const float* __restrict__ bi,
                  const float* __restrict__ Wu, const float* __restrict__ bu,
                  const float* __restrict__ Wo, const float* __restrict__ bo,
                  const float* __restrict__ tf, const float* __restrict__ ti,
                  const float* __restrict__ tu, const float* __restrict__ to_,
                  float* __restrict__ out)
{
    __shared__ float comb[ROWS * CSTRIDE];   // [64][140] combined = [x | h_prev]
    __shared__ float wl[4 * NQ * NF];        // [gate][w][j] = 4*1088 floats
    __shared__ float gz[4 * ROWS * NQ];      // per-gate nonlinearized outputs

    const int tid  = threadIdx.x;
    const int row0 = blockIdx.x * ROWS;

    // ---- stage x tile (64 x 128) coalesced, float4 ----
    const float4* x4 = (const float4*)(x + (size_t)row0 * NIN);
    for (int i = tid; i < ROWS * (NIN / 4); i += THREADS) {
        int r = i >> 5, c4 = i & 31;
        *(float4*)&comb[r * CSTRIDE + c4 * 4] = x4[i];
    }
    // ---- stage h_prev tile (64 x 8) ----
    const float4* h4 = (const float4*)(h_prev + (size_t)row0 * NQ);
    for (int i = tid; i < ROWS * 2; i += THREADS) {
        int r = i >> 1, c4 = i & 1;
        *(float4*)&comb[r * CSTRIDE + NIN + c4 * 4] = h4[i];
    }
    // ---- stage weights: 4 x (8x136) floats ----
    {
        const float4* w4;
        #pragma unroll
        for (int g = 0; g < 4; ++g) {
            w4 = (g == 0) ? (const float4*)Wf : (g == 1) ? (const float4*)Wi
               : (g == 2) ? (const float4*)Wu : (const float4*)Wo;
            for (int i = tid; i < (NQ * NF) / 4; i += THREADS)
                *(float4*)&wl[g * (NQ * NF) + i * 4] = w4[i];
        }
    }
    __syncthreads();

    // ---- per-thread: gate = wave, row = lane ----
    const int g = tid >> 6;     // 0:f 1:i 2:u 3:o  (wave-uniform)
    const int r = tid & 63;

    float acc[NQ] = {0.f, 0.f, 0.f, 0.f, 0.f, 0.f, 0.f, 0.f};
    const float* cb = &comb[r * CSTRIDE];
    const float* wg = &wl[g * (NQ * NF)];

    for (int j4 = 0; j4 < NF / 4; ++j4) {
        float4 xv = *(const float4*)&cb[j4 * 4];
        #pragma unroll
        for (int w = 0; w < NQ; ++w) {
            float4 wv = *(const float4*)&wg[w * NF + j4 * 4];
            acc[w] = fmaf(xv.x, wv.x,
                     fmaf(xv.y, wv.y,
                     fmaf(xv.z, wv.z,
                     fmaf(xv.w, wv.w, acc[w]))));
        }
    }

    // bias + theta, cumulative product of cosines, gate nonlinearity
    const float* bp = (g == 0) ? bf : (g == 1) ? bi : (g == 2) ? bu : bo;
    const float* tp = (g == 0) ? tf : (g == 1) ? ti : (g == 2) ? tu : to_;
    float z = 1.0f;
    #pragma unroll
    for (int w = 0; w < NQ; ++w) {
        z *= cosf(acc[w] + bp[w] + tp[w]);
        float s = sigmoidf_(z);
        gz[g * (ROWS * NQ) + r * NQ + w] = (g == 2) ? tanhf(s) : s;
    }
    __syncthreads();

    // ---- combine: c = f*c_prev + i*g ; h = o*tanh(c) ----
    for (int i = tid; i < ROWS * NQ; i += THREADS) {
        float fv = gz[0 * (ROWS * NQ) + i];
        float iv = gz[1 * (ROWS * NQ) + i];
        float gv = gz[2 * (ROWS * NQ) + i];
        float ov = gz[3 * (ROWS * NQ) + i];
        float cp = c_prev[(size_t)row0 * NQ + i];
        float c  = fv * cp + iv * gv;
        float h  = ov * tanhf(c);
        out[(size_t)row0 * NQ + i]                    = h;  // h first
        out[(size_t)BATCH * NQ + (size_t)row0 * NQ + i] = c;  // then c
    }
}

extern "C" void kernel_launch(void* const* d_in, const int* in_sizes, int n_in,
                              void* d_out, int out_size, void* d_ws, size_t ws_size,
                              hipStream_t stream) {
    const float* x      = (const float*)d_in[0];
    const float* h_prev = (const float*)d_in[1];
    const float* c_prev = (const float*)d_in[2];
    const float* Wf     = (const float*)d_in[3];
    const float* bf     = (const float*)d_in[4];
    const float* Wi     = (const float*)d_in[5];
    const float* bi     = (const float*)d_in[6];
    const float* Wu     = (const float*)d_in[7];
    const float* bu     = (const float*)d_in[8];
    const float* Wo     = (const float*)d_in[9];
    const float* bo     = (const float*)d_in[10];
    const float* tf     = (const float*)d_in[11];
    const float* ti     = (const float*)d_in[12];
    const float* tu     = (const float*)d_in[13];
    const float* to_    = (const float*)d_in[14];
    float* out = (float*)d_out;

    qlstm_kernel<<<BATCH / ROWS, THREADS, 0, stream>>>(
        x, h_prev, c_prev, Wf, bf, Wi, bi, Wu, bu, Wo, bo, tf, ti, tu, to_, out);
}

// Round 2
// 12.358 us; speedup vs baseline: 1.2466x; 1.2466x over previous
//
#include <hip/hip_runtime.h>

#define NQ      8
#define NIN     128
#define NF      136          // NIN + NQ
#define BATCH   4096
#define RPB     8            // rows per block
#define THREADS 256          // 8 rows x 32 (4 gates x 8 wires)

__device__ __forceinline__ float fast_sigmoid(float v) {
    return 1.0f / (1.0f + __expf(-v));
}
__device__ __forceinline__ float fast_tanh(float v) {
    // tanh(x) = 1 - 2/(exp(2x)+1); |v| bounded (~<6) in this problem
    return 1.0f - 2.0f / (__expf(2.0f * v) + 1.0f);
}

__global__ __launch_bounds__(THREADS)
void qlstm_kernel(const float* __restrict__ x,
                  const float* __restrict__ h_prev,
                  const float* __restrict__ c_prev,
                  const float* __restrict__ Wf, const float* __restrict__ bf,
                  const float* __restrict__ Wi, const float* __restrict__ bi,
                  const float* __restrict__ Wu, const float* __restrict__ bu,
                  const float* __restrict__ Wo, const float* __restrict__ bo,
                  const float* __restrict__ tf, const float* __restrict__ ti,
                  const float* __restrict__ tu, const float* __restrict__ to_,
                  float* __restrict__ out)
{
    const int tid = threadIdx.x;
    const int lr  = tid >> 5;                    // local row 0..7
    const int gw  = tid & 31;
    const int g   = gw >> 3;                     // gate 0:f 1:i 2:u 3:o
    const int w   = gw & 7;                      // wire
    const int row = blockIdx.x * RPB + lr;

    const float* Wg = (g == 0) ? Wf : (g == 1) ? Wi : (g == 2) ? Wu : Wo;
    const float* bp = (g == 0) ? bf : (g == 1) ? bi : (g == 2) ? bu : bo;
    const float* tp = (g == 0) ? tf : (g == 1) ? ti : (g == 2) ? tu : to_;

    // dot(combined[row], Wg[w]) : x part (128) + h_prev part (8)
    const float4* xr = (const float4*)(x + (size_t)row * NIN);        // broadcast within 32-lane group
    const float4* wr = (const float4*)(Wg + w * NF);                  // L1-resident (17 KB total)
    const float4* hr = (const float4*)(h_prev + (size_t)row * NQ);
    const float4* wh = (const float4*)(Wg + w * NF + NIN);

    float acc = 0.0f;
    #pragma unroll 8
    for (int j = 0; j < NIN / 4; ++j) {
        float4 xv = xr[j];
        float4 wv = wr[j];
        acc = fmaf(xv.x, wv.x,
              fmaf(xv.y, wv.y,
              fmaf(xv.z, wv.z,
              fmaf(xv.w, wv.w, acc))));
    }
    #pragma unroll
    for (int j = 0; j < NQ / 4; ++j) {
        float4 xv = hr[j];
        float4 wv = wh[j];
        acc = fmaf(xv.x, wv.x,
              fmaf(xv.y, wv.y,
              fmaf(xv.z, wv.z,
              fmaf(xv.w, wv.w, acc))));
    }

    // angle -> cos -> inclusive product scan over the 8 wires of this gate
    float a  = acc + bp[w] + tp[w];
    float v  = __cosf(a);
    #pragma unroll
    for (int d = 1; d < NQ; d <<= 1) {
        float t = __shfl_up(v, d, NQ);           // scan within 8-lane wire group
        if (w >= d) v *= t;
    }

    float s = fast_sigmoid(v);
    if (g == 2) s = fast_tanh(s);                // u-gate: tanh(sigmoid(.))

    // gather the 4 gate values for (row, w) from the 32-lane row group
    const int rb = tid & 32;                     // row-group base within the wave
    float fv = __shfl(s, rb | w,        64);
    float iv = __shfl(s, rb | (8  + w), 64);
    float uv = __shfl(s, rb | (16 + w), 64);
    float ov = __shfl(s, rb | (24 + w), 64);

    if (g == 0) {
        float cp = c_prev[(size_t)row * NQ + w];
        float c  = fv * cp + iv * uv;
        float h  = ov * fast_tanh(c);
        out[(size_t)row * NQ + w]                      = h;  // h first
        out[(size_t)BATCH * NQ + (size_t)row * NQ + w] = c;  // then c
    }
}

extern "C" void kernel_launch(void* const* d_in, const int* in_sizes, int n_in,
                              void* d_out, int out_size, void* d_ws, size_t ws_size,
                              hipStream_t stream) {
    const float* x      = (const float*)d_in[0];
    const float* h_prev = (const float*)d_in[1];
    const float* c_prev = (const float*)d_in[2];
    const float* Wf     = (const float*)d_in[3];
    const float* bf     = (const float*)d_in[4];
    const float* Wi     = (const float*)d_in[5];
    const float* bi     = (const float*)d_in[6];
    const float* Wu     = (const float*)d_in[7];
    const float* bu     = (const float*)d_in[8];
    const float* Wo     = (const float*)d_in[9];
    const float* bo     = (const float*)d_in[10];
    const float* tf     = (const float*)d_in[11];
    const float* ti     = (const float*)d_in[12];
    const float* tu     = (const float*)d_in[13];
    const float* to_    = (const float*)d_in[14];
    float* out = (float*)d_out;

    qlstm_kernel<<<BATCH / RPB, THREADS, 0, stream>>>(
        x, h_prev, c_prev, Wf, bf, Wi, bi, Wu, bu, Wo, bo, tf, ti, tu, to_, out);
}

// Round 3
// 12.180 us; speedup vs baseline: 1.2649x; 1.0147x over previous
//
#include <hip/hip_runtime.h>

#define NQ      8
#define NIN     128
#define NF      136          // NIN + NQ
#define BATCH   4096
#define RPB     4            // rows per block (1 row per wave64)
#define THREADS 256
#define NBLK    (BATCH / RPB)   // 1024

__device__ __forceinline__ float fast_sigmoid(float v) {
    return 1.0f / (1.0f + __expf(-v));
}
__device__ __forceinline__ float fast_tanh(float v) {
    return 1.0f - 2.0f / (__expf(2.0f * v) + 1.0f);
}
__device__ __forceinline__ float fma4(float4 a, float4 b, float acc) {
    return fmaf(a.x, b.x, fmaf(a.y, b.y, fmaf(a.z, b.z, fmaf(a.w, b.w, acc))));
}

__global__ __launch_bounds__(THREADS)
void qlstm_kernel(const float* __restrict__ x,
                  const float* __restrict__ h_prev,
                  const float* __restrict__ c_prev,
                  const float* __restrict__ Wf, const float* __restrict__ bf,
                  const float* __restrict__ Wi, const float* __restrict__ bi,
                  const float* __restrict__ Wu, const float* __restrict__ bu,
                  const float* __restrict__ Wo, const float* __restrict__ bo,
                  const float* __restrict__ tf, const float* __restrict__ ti,
                  const float* __restrict__ tu, const float* __restrict__ to_,
                  float* __restrict__ out)
{
    const int tid  = threadIdx.x;
    const int lr   = tid >> 6;                   // wave index = local row 0..3
    const int lane = tid & 63;
    const int half = lane >> 5;                  // which half of the dot
    const int gw   = lane & 31;
    const int g    = gw >> 3;                    // gate 0:f 1:i 2:u 3:o
    const int w    = gw & 7;                     // wire
    const int row  = blockIdx.x * RPB + lr;

    const float* Wg = (g == 0) ? Wf : (g == 1) ? Wi : (g == 2) ? Wu : Wo;
    const float* bp = (g == 0) ? bf : (g == 1) ? bi : (g == 2) ? bu : bo;
    const float* tp = (g == 0) ? tf : (g == 1) ? ti : (g == 2) ? tu : to_;

    const float4* xr = (const float4*)(x + (size_t)row * NIN);
    const float4* wr = (const float4*)(Wg + w * NF);
    const int     jb = half * 16;                // float4 base into x-row

    // ---- half-split dot: 16 x-f4 + 1 h-f4 per thread, uniform control flow ----
    float acc = 0.0f;
    #pragma unroll
    for (int j = 0; j < 16; ++j)
        acc = fma4(xr[jb + j], wr[jb + j], acc);

    float4 hv = ((const float4*)(h_prev + (size_t)row * NQ))[half];
    float4 wh = ((const float4*)(Wg + w * NF + NIN))[half];
    acc = fma4(hv, wh, acc);

    acc += __shfl_xor(acc, 32, 64);              // combine halves (both now hold full dot)

    // ---- angle -> cos -> inclusive product scan over the 8 wires ----
    float a = acc + bp[w] + tp[w];
    float v = __cosf(a);
    #pragma unroll
    for (int d = 1; d < NQ; d <<= 1) {
        float t = __shfl_up(v, d, NQ);
        if (w >= d) v *= t;
    }

    float s = fast_sigmoid(v);
    if (g == 2) s = fast_tanh(s);                // u-gate: tanh(sigmoid(.))

    // ---- gather the 4 gate values for (row, w) within this half's 32-lane group ----
    const int rb = lane & 32;
    float fv = __shfl(s, rb | w,        64);
    float iv = __shfl(s, rb | (8  + w), 64);
    float uv = __shfl(s, rb | (16 + w), 64);
    float ov = __shfl(s, rb | (24 + w), 64);

    if (g == 0) {
        float cp = c_prev[(size_t)row * NQ + w];
        float c  = fv * cp + iv * uv;
        if (half == 0) {
            float h = ov * fast_tanh(c);
            out[(size_t)row * NQ + w] = h;                       // h
        } else {
            out[(size_t)BATCH * NQ + (size_t)row * NQ + w] = c;  // c
        }
    }
}

extern "C" void kernel_launch(void* const* d_in, const int* in_sizes, int n_in,
                              void* d_out, int out_size, void* d_ws, size_t ws_size,
                              hipStream_t stream) {
    const float* x      = (const float*)d_in[0];
    const float* h_prev = (const float*)d_in[1];
    const float* c_prev = (const float*)d_in[2];
    const float* Wf     = (const float*)d_in[3];
    const float* bf     = (const float*)d_in[4];
    const float* Wi     = (const float*)d_in[5];
    const float* bi     = (const float*)d_in[6];
    const float* Wu     = (const float*)d_in[7];
    const float* bu     = (const float*)d_in[8];
    const float* Wo     = (const float*)d_in[9];
    const float* bo     = (const float*)d_in[10];
    const float* tf     = (const float*)d_in[11];
    const float* ti     = (const float*)d_in[12];
    const float* tu     = (const float*)d_in[13];
    const float* to_    = (const float*)d_in[14];
    float* out = (float*)d_out;

    qlstm_kernel<<<NBLK, THREADS, 0, stream>>>(
        x, h_prev, c_prev, Wf, bf, Wi, bi, Wu, bu, Wo, bo, tf, ti, tu, to_, out);
}